// Round 11
// baseline (147.383 us; speedup 1.0000x reference)
//
#include <hip/hip_runtime.h>
#include <hip/hip_bf16.h>
#include <stdint.h>

#define BATCH 8192
#define DIM   1024
#define BM 128
#define BN 64
#define BK 64
#define NT 16
#define NTILE 1024   // (8192/128) * (1024/64)

typedef __attribute__((ext_vector_type(4))) float f32x4;
typedef __attribute__((ext_vector_type(8))) short bf16x8;
typedef __attribute__((ext_vector_type(4))) unsigned short u16x4;
typedef __attribute__((ext_vector_type(8))) unsigned short u16x8;

#define AS1(p) ((const __attribute__((address_space(1))) void*)(p))
#define AS3(p) ((__attribute__((address_space(3))) void*)(p))

__device__ __forceinline__ unsigned short f2bf(float f) {
    union { __hip_bfloat16 h; unsigned short u; } v;
    v.h = __hip_bfloat16(f);
    return v.u;
}
__device__ __forceinline__ float bf2f(unsigned short u) {
    union { unsigned int i; float f; } v; v.i = (unsigned int)u << 16;
    return v.f;
}
__device__ __forceinline__ float sigma_f(float x) {
    float x2 = x * x;
    return x2 * __builtin_amdgcn_rcpf(1.0f + x2);
}

// ---------------------------------------------------------------------------
// Kernel 1: convert A to bf16 + zero the queue header (every launch).
// ---------------------------------------------------------------------------
__global__ __launch_bounds__(256) void convA_kernel(
    const float* __restrict__ A, unsigned short* __restrict__ Ab,
    unsigned* __restrict__ hdr)
{
    int idx = blockIdx.x * 256 + threadIdx.x;
    if (idx < 2 + NTILE) hdr[idx] = 0;           // counters + q[]
    f32x4 av = ((const f32x4*)A)[idx];
    u16x4 ab;
#pragma unroll
    for (int i = 0; i < 4; ++i) ab[i] = f2bf(av[i]);
    ((u16x4*)Ab)[idx] = ab;
}

// ---------------------------------------------------------------------------
// Kernel 2: queue-mediated cross-block GEMM/epilogue pipeline.
//   512 blocks (2/CU), 256 thr (4 waves, 2x2), tile 128x64, NTILE=1024
//   (each block owns tiles T0=bsw, T1=bsw+512).
//   gemmTile: R9-verified K-loop -> acc -> LDS -> Cws (bf16, ws).
//   push: __syncthreads (vmcnt drain) -> tid0 release-store tile into q.
//   popEpi: tid0 takes ticket, polls relaxed + acquire (L2 inv), block
//           streams epilogue for that tile (reads Cws + x/ex/W, writes out0/1).
//   Parity schedules de-phase the two resident blocks per CU:
//     even: G0,G1,zeros,E,E   odd: G0,E,zeros,G1,E
//   Deadlock-free: every block pushes >=k tiles before its k-th pop.
// ---------------------------------------------------------------------------
__global__ __launch_bounds__(256, 2) void fused_kernel(
    const float* __restrict__ x, const float* __restrict__ ex,
    const float* __restrict__ W, const float* __restrict__ tgt,
    const unsigned short* __restrict__ Ab,
    unsigned short* __restrict__ Cws, unsigned* __restrict__ hdr,
    float* __restrict__ out0, float* __restrict__ out1,
    float* __restrict__ out2)
{
    __shared__ __align__(16) char lds[81920];    // dbuf 2x24K staging + 32K C
    __shared__ int shE;
    char* Cl = lds + 49152;

    const int b   = blockIdx.x;
    const int bsw = (b & 7) * 64 + (b >> 3);     // XCD-contiguous tile map
    const int T0  = bsw, T1 = bsw + 512;

    const int tid  = threadIdx.x;
    const int lane = tid & 63;
    const int wid  = tid >> 6;
    const int wr   = wid >> 1, wc = wid & 1;
    const int l15  = lane & 15;
    const int swz  = (((lane & 7) ^ (lane >> 3)) << 4);
    const int r0   = tid >> 3;
    const int g    = tid & 7;
    const int wAoff = (g * 16) ^ ((r0 & 7) << 4);
    const int rd_sw = (lane & 7) << 4;
    const int cb0   = (lane >> 4) << 4;

    unsigned* q = hdr + 2;

    // ---------------- GEMM one tile, leave C (bf16) in Cws ----------------
    auto gemmTile = [&](int t) {
        const int bm = t >> 4, bn = t & 15;
        const float* gx = x + (size_t)(bm * BM + r0) * DIM + g * 8;
        const char* gBb = (const char*)Ab +
            ((size_t)(bn * BN + wid * 8 + (lane >> 3)) * DIM) * 2 + swz;

        f32x4 acc[4][2];
#pragma unroll
        for (int mi = 0; mi < 4; ++mi)
#pragma unroll
            for (int ni = 0; ni < 2; ++ni)
                acc[mi][ni] = f32x4{0.f, 0.f, 0.f, 0.f};

        auto stageB = [&](int k, char* Bs) {
#pragma unroll
            for (int j = 0; j < 2; ++j)
                __builtin_amdgcn_global_load_lds(
                    AS1(gBb + (size_t)j * (32 * DIM * 2) + (size_t)k * 2),
                    AS3(Bs + (wid * 8 + j * 32) * 128), 16, 0, 0);
        };
        auto loadX = [&](int k, f32x4 xa[4][2]) {
#pragma unroll
            for (int s = 0; s < 4; ++s) {
                xa[s][0] = *(const f32x4*)(gx + (size_t)s * 32 * DIM + k);
                xa[s][1] = *(const f32x4*)(gx + (size_t)s * 32 * DIM + k + 4);
            }
        };
        auto writeSig = [&](char* As, f32x4 xa[4][2]) {
#pragma unroll
            for (int s = 0; s < 4; ++s) {
                u16x8 sb;
#pragma unroll
                for (int i = 0; i < 4; ++i) {
                    sb[i]     = f2bf(sigma_f(xa[s][0][i]));
                    sb[i + 4] = f2bf(sigma_f(xa[s][1][i]));
                }
                *(u16x8*)(As + (r0 + s * 32) * 128 + wAoff) = sb;
            }
        };

        {   // prologue
            f32x4 xa[4][2];
            loadX(0, xa);
            stageB(0, lds + 16384);
            writeSig(lds, xa);
        }
        __syncthreads();

        for (int it = 0; it < NT; ++it) {
            const int cur = it & 1;
            char* bufn = lds + (cur ^ 1) * 24576;
            f32x4 xa[4][2];
            if (it + 1 < NT) {
                loadX((it + 1) * BK, xa);
                stageB((it + 1) * BK, bufn + 16384);
            }
            __builtin_amdgcn_sched_barrier(0);
            const char* As_ = lds + cur * 24576;
            const char* Bs_ = As_ + 16384;
#pragma unroll
            for (int kk = 0; kk < 2; ++kk) {
                bf16x8 af[4], bfr[2];
#pragma unroll
                for (int mi = 0; mi < 4; ++mi)
                    af[mi] = *(const bf16x8*)(As_ + (wr * 64 + mi * 16 + l15) * 128 +
                                              ((cb0 + kk * 64) ^ rd_sw));
#pragma unroll
                for (int ni = 0; ni < 2; ++ni)
                    bfr[ni] = *(const bf16x8*)(Bs_ + (wc * 32 + ni * 16 + l15) * 128 +
                                               ((cb0 + kk * 64) ^ rd_sw));
#pragma unroll
                for (int mi = 0; mi < 4; ++mi)
#pragma unroll
                    for (int ni = 0; ni < 2; ++ni)
                        acc[mi][ni] = __builtin_amdgcn_mfma_f32_16x16x32_bf16(
                            af[mi], bfr[ni], acc[mi][ni], 0, 0, 0);
            }
            __builtin_amdgcn_sched_barrier(0);
            if (it + 1 < NT) writeSig(bufn, xa);
            __syncthreads();
        }

        // acc -> LDS f32 [128][64] linear
#pragma unroll
        for (int mi = 0; mi < 4; ++mi)
#pragma unroll
            for (int ni = 0; ni < 2; ++ni) {
                const int row_ = wr * 64 + mi * 16 + ((lane >> 4) << 2);
                const int colb = (wc * 32 + ni * 16 + l15) * 4;
#pragma unroll
                for (int r = 0; r < 4; ++r)
                    *(float*)(Cl + (row_ + r) * 256 + colb) = acc[mi][ni][r];
            }
        __syncthreads();

        // LDS -> Cws bf16 (coalesced)
        u16x4* Cq = (u16x4*)Cws + (size_t)t * 2048;
#pragma unroll
        for (int p = 0; p < 8; ++p) {
            const int ci = p * 256 + tid, row = ci >> 4, cv = ci & 15;
            f32x4 c = *(const f32x4*)(Cl + row * 256 + cv * 16);
            u16x4 cb;
#pragma unroll
            for (int e = 0; e < 4; ++e) cb[e] = f2bf(c[e]);
            Cq[ci] = cb;
        }
        __syncthreads();   // drains vmcnt for ALL waves before the push
    };

    auto pushT = [&](int t) {
        if (tid == 0) {
            unsigned slot = atomicAdd(&hdr[0], 1u);
            __hip_atomic_store(&q[slot], (unsigned)(t + 1),
                               __ATOMIC_RELEASE, __HIP_MEMORY_SCOPE_AGENT);
        }
    };

    auto popEpi = [&]() {
        if (tid == 0) {
            unsigned tk = atomicAdd(&hdr[1], 1u);
            unsigned v;
            for (;;) {
                v = __hip_atomic_load(&q[tk], __ATOMIC_RELAXED,
                                      __HIP_MEMORY_SCOPE_AGENT);
                if (v) break;
                __builtin_amdgcn_s_sleep(2);
            }
            (void)__hip_atomic_load(&q[tk], __ATOMIC_ACQUIRE,
                                    __HIP_MEMORY_SCOPE_AGENT);  // L2 inv
            shE = (int)v - 1;
        }
        __syncthreads();
        const int e   = shE;
        const int ebm = e >> 4, ebn = e & 15;
        const u16x4* Cq = (const u16x4*)Cws + (size_t)e * 2048;
#pragma unroll
        for (int p = 0; p < 8; ++p) {
            const int ci = p * 256 + tid, row = ci >> 4, cv = ci & 15;
            u16x4 cb = Cq[ci];
            const size_t v4 = (size_t)(ebm * BM + row) * (DIM / 4) + ebn * 16 + cv;
            f32x4 xv = ((const f32x4*)x)[v4];
            f32x4 evv = ((const f32x4*)ex)[v4];
            f32x4 wv = ((const f32x4*)W)[v4];
            f32x4 tv = ((const f32x4*)tgt)[ebn * 16 + cv];
            f32x4 o0;
#pragma unroll
            for (int ee = 0; ee < 4; ++ee) {
                float xi = xv[ee], ti = tv[ee];
                float ba = ti * ti * __builtin_amdgcn_rcpf(1.0f + ti * ti);
                float u  = -(wv[ee] * (xi + evv[ee] - ti)) * ba;
                float s  = sigma_f(xi);
                o0[ee] = -xi + u * s + bf2f(cb[ee]);
            }
            ((f32x4*)out0)[v4] = o0;
            ((f32x4*)out1)[v4] = -o0;
        }
        __syncthreads();   // protect shE reuse
    };

    auto zeroT = [&](int t) {
        const int zbm = t >> 4, zbn = t & 15;
#pragma unroll
        for (int p = 0; p < 8; ++p) {
            const int ci = p * 256 + tid, row = ci >> 4, cv = ci & 15;
            ((f32x4*)out2)[(size_t)(zbm * BM + row) * (DIM / 4) + zbn * 16 + cv] =
                f32x4{0.f, 0.f, 0.f, 0.f};
        }
    };

    // ---------------- parity-staggered schedule ----------------
    gemmTile(T0); pushT(T0);
    if (b & 1) {
        popEpi();
        zeroT(T0); zeroT(T1);
        gemmTile(T1); pushT(T1);
        popEpi();
    } else {
        gemmTile(T1); pushT(T1);
        zeroT(T0); zeroT(T1);
        popEpi(); popEpi();
    }
}

// ---------------------------------------------------------------------------
extern "C" void kernel_launch(void* const* d_in, const int* in_sizes, int n_in,
                              void* d_out, int out_size, void* d_ws, size_t ws_size,
                              hipStream_t stream)
{
    const float* x   = (const float*)d_in[0];
    const float* ex  = (const float*)d_in[1];
    const float* W   = (const float*)d_in[2];
    const float* A   = (const float*)d_in[3];
    const float* tgt = (const float*)d_in[4];

    float* out0 = (float*)d_out;
    float* out1 = out0 + (size_t)BATCH * DIM;
    float* out2 = out1 + (size_t)BATCH * DIM;

    unsigned short* Abf = (unsigned short*)d_ws;                                   // 2 MiB
    unsigned short* Cws = (unsigned short*)((char*)d_ws + (size_t)2 * 1024 * 1024); // 16 MiB
    unsigned*       hdr = (unsigned*)((char*)d_ws + (size_t)18 * 1024 * 1024);      // ~4.1 KiB

    convA_kernel<<<DIM * DIM / 4 / 256, 256, 0, stream>>>(A, Abf, hdr);
    fused_kernel<<<512, 256, 0, stream>>>(x, ex, W, tgt, Abf, Cws, hdr,
                                          out0, out1, out2);
}

// Round 12
// 111.587 us; speedup vs baseline: 1.3208x; 1.3208x over previous
//
#include <hip/hip_runtime.h>
#include <hip/hip_bf16.h>
#include <stdint.h>

#define BATCH 8192
#define DIM   1024
#define BM 128
#define BN 64
#define BK 64
#define NT 16
#define NV4 (BATCH * DIM / 4)    // 2097152

typedef __attribute__((ext_vector_type(4))) float f32x4;
typedef __attribute__((ext_vector_type(8))) short bf16x8;
typedef __attribute__((ext_vector_type(4))) unsigned short u16x4;
typedef __attribute__((ext_vector_type(8))) unsigned short u16x8;

__device__ __forceinline__ unsigned short f2bf(float f) {
    union { __hip_bfloat16 h; unsigned short u; } v;
    v.h = __hip_bfloat16(f);
    return v.u;
}
__device__ __forceinline__ float bf2f(unsigned short u) {
    union { unsigned int i; float f; } v; v.i = (unsigned int)u << 16;
    return v.f;
}
__device__ __forceinline__ float sigma_f(float x) {
    float x2 = x * x;
    return x2 * __builtin_amdgcn_rcpf(1.0f + x2);
}

// ---------------------------------------------------------------------------
// K1: heterogeneous grid, 2048 blocks x 256 thr, NO cross-block deps.
//   Role G ((b>>3)&1 == 0, 1024 blocks): GEMM 128x64 tile -> C bf16 in ws.
//     A-operand sigma(x) and B-operand bf16(A) both reg-staged from f32
//     (convA kernel eliminated). Verified R9 addressing throughout.
//   Role S (1024 blocks): streaming base-pass: read x/ex/W, write
//     base -> out0, zeros -> out2. Pure BW, no LDS use, no barriers.
//   Roles interleave in groups of 8 so XCD round-robin mixes them; disjoint
//   output buffers; GEMM is latency/MFMA-bound, streamers eat the HBM pipe.
// ---------------------------------------------------------------------------
__global__ __launch_bounds__(256, 3) void k1_kernel(
    const float* __restrict__ x, const float* __restrict__ ex,
    const float* __restrict__ W, const float* __restrict__ tgt,
    const float* __restrict__ A,
    unsigned short* __restrict__ Cws,
    float* __restrict__ out0, float* __restrict__ out2)
{
    __shared__ __align__(16) char lds[49152];   // G: dbuf 2 x {As 16K | Bs 8K}

    const int b = blockIdx.x;
    const int tid = threadIdx.x;

    if (((b >> 3) & 1) == 0) {
        // ================= Role G: GEMM =================
        const int gt = (b >> 4) * 8 + (b & 7);   // 0..1023
        const int bm = gt >> 4;                  // 0..63
        const int bn = gt & 15;                  // 0..15

        const int lane = tid & 63;
        const int wid  = tid >> 6;               // 0..3
        const int wr   = wid >> 1, wc = wid & 1;
        const int l15  = lane & 15;
        const int r0   = tid >> 3;               // 0..31
        const int g    = tid & 7;
        const int wAoff = (g * 16) ^ ((r0 & 7) << 4);
        const int rd_sw = (lane & 7) << 4;
        const int cb0   = (lane >> 4) << 4;

        const float* gx = x + (size_t)(bm * BM + r0) * DIM + g * 8;
        const float* gA = A + (size_t)(bn * BN + r0) * DIM + g * 8;

        f32x4 acc[4][2];
#pragma unroll
        for (int mi = 0; mi < 4; ++mi)
#pragma unroll
            for (int ni = 0; ni < 2; ++ni)
                acc[mi][ni] = f32x4{0.f, 0.f, 0.f, 0.f};

        f32x4 xa[4][2], bv[2][2];

        auto loadX = [&](int k) {
#pragma unroll
            for (int s = 0; s < 4; ++s) {
                xa[s][0] = *(const f32x4*)(gx + (size_t)s * 32 * DIM + k);
                xa[s][1] = *(const f32x4*)(gx + (size_t)s * 32 * DIM + k + 4);
            }
        };
        auto loadB = [&](int k) {
#pragma unroll
            for (int s = 0; s < 2; ++s) {
                bv[s][0] = *(const f32x4*)(gA + (size_t)s * 32 * DIM + k);
                bv[s][1] = *(const f32x4*)(gA + (size_t)s * 32 * DIM + k + 4);
            }
        };
        auto writeStage = [&](char* buf) {
            char* As = buf;
            char* Bs = buf + 16384;
#pragma unroll
            for (int s = 0; s < 4; ++s) {
                u16x8 sb;
#pragma unroll
                for (int i = 0; i < 4; ++i) {
                    sb[i]     = f2bf(sigma_f(xa[s][0][i]));
                    sb[i + 4] = f2bf(sigma_f(xa[s][1][i]));
                }
                *(u16x8*)(As + (r0 + s * 32) * 128 + wAoff) = sb;
            }
#pragma unroll
            for (int s = 0; s < 2; ++s) {
                u16x8 sb;
#pragma unroll
                for (int i = 0; i < 4; ++i) {
                    sb[i]     = f2bf(bv[s][0][i]);
                    sb[i + 4] = f2bf(bv[s][1][i]);
                }
                *(u16x8*)(Bs + (r0 + s * 32) * 128 + wAoff) = sb;
            }
        };

        loadX(0); loadB(0);
        writeStage(lds);
        __syncthreads();

        for (int t = 0; t < NT; ++t) {
            const int cur = t & 1;
            if (t + 1 < NT) { loadX((t + 1) * BK); loadB((t + 1) * BK); }
            __builtin_amdgcn_sched_barrier(0);

            const char* As_ = lds + cur * 24576;
            const char* Bs_ = As_ + 16384;
#pragma unroll
            for (int kk = 0; kk < 2; ++kk) {
                bf16x8 af[4], bfr[2];
#pragma unroll
                for (int mi = 0; mi < 4; ++mi)
                    af[mi] = *(const bf16x8*)(As_ + (wr * 64 + mi * 16 + l15) * 128 +
                                              ((cb0 + kk * 64) ^ rd_sw));
#pragma unroll
                for (int ni = 0; ni < 2; ++ni)
                    bfr[ni] = *(const bf16x8*)(Bs_ + (wc * 32 + ni * 16 + l15) * 128 +
                                               ((cb0 + kk * 64) ^ rd_sw));
#pragma unroll
                for (int mi = 0; mi < 4; ++mi)
#pragma unroll
                    for (int ni = 0; ni < 2; ++ni)
                        acc[mi][ni] = __builtin_amdgcn_mfma_f32_16x16x32_bf16(
                            af[mi], bfr[ni], acc[mi][ni], 0, 0, 0);
            }
            __builtin_amdgcn_sched_barrier(0);
            if (t + 1 < NT) writeStage(lds + (cur ^ 1) * 24576);
            __syncthreads();
        }

        // acc -> LDS f32 [128][64] linear
#pragma unroll
        for (int mi = 0; mi < 4; ++mi)
#pragma unroll
            for (int ni = 0; ni < 2; ++ni) {
                const int row_ = wr * 64 + mi * 16 + ((lane >> 4) << 2);
                const int colb = (wc * 32 + ni * 16 + l15) * 4;
#pragma unroll
                for (int r = 0; r < 4; ++r)
                    *(float*)(lds + (row_ + r) * 256 + colb) = acc[mi][ni][r];
            }
        __syncthreads();

        // LDS -> Cws bf16 (coalesced 16B stores)
        unsigned short* Ct = Cws + (size_t)gt * (BM * BN);
#pragma unroll
        for (int p = 0; p < 4; ++p) {
            const int ci  = p * 256 + tid;       // 0..1023
            const int row = ci >> 3;             // 0..127
            const int gg  = ci & 7;              // 8B-group of 8 elems
            f32x4 c0 = *(const f32x4*)(lds + row * 256 + gg * 32);
            f32x4 c1 = *(const f32x4*)(lds + row * 256 + gg * 32 + 16);
            u16x8 cb;
#pragma unroll
            for (int e = 0; e < 4; ++e) {
                cb[e]     = f2bf(c0[e]);
                cb[e + 4] = f2bf(c1[e]);
            }
            *(u16x8*)(Ct + row * BN + gg * 8) = cb;
        }
    } else {
        // ================= Role S: streaming base-pass =================
        const int s = (b >> 4) * 8 + (b & 7);    // 0..1023
        const int i0 = s * 256 + tid;
#pragma unroll
        for (int p = 0; p < 8; ++p) {
            const int v4 = i0 + p * 262144;
            const int cv = v4 & 255;
            f32x4 xv = ((const f32x4*)x)[v4];
            f32x4 ev = ((const f32x4*)ex)[v4];
            f32x4 wv = ((const f32x4*)W)[v4];
            f32x4 tv = ((const f32x4*)tgt)[cv];
            f32x4 bq;
#pragma unroll
            for (int e = 0; e < 4; ++e) {
                float xi = xv[e], ti = tv[e];
                float ba = ti * ti * __builtin_amdgcn_rcpf(1.0f + ti * ti);
                float u  = -(wv[e] * (xi + ev[e] - ti)) * ba;
                float sg = sigma_f(xi);
                bq[e] = -xi + u * sg;
            }
            ((f32x4*)out0)[v4] = bq;
            ((f32x4*)out2)[v4] = f32x4{0.f, 0.f, 0.f, 0.f};
        }
    }
}

// ---------------------------------------------------------------------------
// K2: merge. out0 = base + C, out1 = -(base + C). 112 MB pure streaming.
// ---------------------------------------------------------------------------
__global__ __launch_bounds__(256) void k2_kernel(
    const unsigned short* __restrict__ Cws,
    float* __restrict__ out0, float* __restrict__ out1)
{
    const int i0 = blockIdx.x * 256 + threadIdx.x;
#pragma unroll
    for (int p = 0; p < 4; ++p) {
        const int v4  = i0 + p * 524288;
        const int m   = v4 >> 8;                 // row 0..8191
        const int cv  = v4 & 255;                // f32x4 col
        const int gt  = (m >> 7) * 16 + (cv >> 4);
        const int off = (m & 127) * BN + (cv & 15) * 4;
        u16x4 cb = *(const u16x4*)(Cws + (size_t)gt * (BM * BN) + off);
        f32x4 bq = ((const f32x4*)out0)[v4];
        f32x4 o0;
#pragma unroll
        for (int e = 0; e < 4; ++e) o0[e] = bq[e] + bf2f(cb[e]);
        ((f32x4*)out0)[v4] = o0;
        ((f32x4*)out1)[v4] = -o0;
    }
}

// ---------------------------------------------------------------------------
extern "C" void kernel_launch(void* const* d_in, const int* in_sizes, int n_in,
                              void* d_out, int out_size, void* d_ws, size_t ws_size,
                              hipStream_t stream)
{
    const float* x   = (const float*)d_in[0];
    const float* ex  = (const float*)d_in[1];
    const float* W   = (const float*)d_in[2];
    const float* A   = (const float*)d_in[3];
    const float* tgt = (const float*)d_in[4];

    float* out0 = (float*)d_out;
    float* out1 = out0 + (size_t)BATCH * DIM;
    float* out2 = out1 + (size_t)BATCH * DIM;

    unsigned short* Cws = (unsigned short*)d_ws;   // 16 MiB

    k1_kernel<<<2048, 256, 0, stream>>>(x, ex, W, tgt, A, Cws, out0, out2);
    k2_kernel<<<2048, 256, 0, stream>>>(Cws, out0, out1);
}

// Round 13
// 55.708 us; speedup vs baseline: 2.6456x; 2.0031x over previous
//
#include <hip/hip_runtime.h>
#include <hip/hip_bf16.h>
#include <stdint.h>

#define BATCH 8192
#define DIM   1024
#define BM 128
#define BN 64
#define BK 64
#define STEPS 16                 // DIM / BK
#define BUF 24576                // A 16K + B 8K per stage buffer

typedef __attribute__((ext_vector_type(4))) float f32x4;
typedef __attribute__((ext_vector_type(8))) short bf16x8;
typedef __attribute__((ext_vector_type(8))) unsigned short u16x8;

#define AS1(p) ((const __attribute__((address_space(1))) void*)(p))
#define AS3(p) ((__attribute__((address_space(3))) void*)(p))

__device__ __forceinline__ unsigned short f2bf(float f) {
    union { __hip_bfloat16 h; unsigned short u; } v;
    v.h = __hip_bfloat16(f);
    return v.u;
}
__device__ __forceinline__ float sigma_f(float x) {
    float x2 = x * x;
    return x2 * __builtin_amdgcn_rcpf(1.0f + x2);
}

// ---------------------------------------------------------------------------
// K1: sigma(x) -> bf16 ws  (4096 blocks)  |  A -> bf16 ws  (512 blocks)
// ---------------------------------------------------------------------------
__global__ __launch_bounds__(256) void prep_kernel(
    const float* __restrict__ x, const float* __restrict__ A,
    unsigned short* __restrict__ sigb, unsigned short* __restrict__ Abf)
{
    const int i = blockIdx.x * 256 + threadIdx.x;
    if (i < BATCH * DIM / 8) {
        f32x4 v0 = ((const f32x4*)x)[i * 2];
        f32x4 v1 = ((const f32x4*)x)[i * 2 + 1];
        u16x8 sb;
#pragma unroll
        for (int e = 0; e < 4; ++e) {
            sb[e]     = f2bf(sigma_f(v0[e]));
            sb[e + 4] = f2bf(sigma_f(v1[e]));
        }
        ((u16x8*)sigb)[i] = sb;
    } else {
        const int j = i - BATCH * DIM / 8;       // < 131072
        f32x4 v0 = ((const f32x4*)A)[j * 2];
        f32x4 v1 = ((const f32x4*)A)[j * 2 + 1];
        u16x8 ab;
#pragma unroll
        for (int e = 0; e < 4; ++e) {
            ab[e]     = f2bf(v0[e]);
            ab[e + 4] = f2bf(v1[e]);
        }
        ((u16x8*)Abf)[j] = ab;
    }
}

// ---------------------------------------------------------------------------
// K2: GEMM 128x64 tile, pure-glds staging, depth-2 counted-vmcnt pipeline.
//   1024 blocks (2/CU), 4 waves (2x2: 64x32/wave, acc[4][2]).
//   LDS 72 KiB = 3 stage buffers x {A 16K | B 8K}; C-dump reuses [0,32K).
//   Per step: vmcnt(6) -> raw s_barrier -> issue stage(t+2) (6 glds/wave)
//   -> ds_read + 16 MFMA. Loads span 2 iterations; barrier never drains.
//   Epilogue: C -> LDS, then streaming pass recomputes base from x/ex/W
//   and writes out0/out1/out2 (fully f32x4-coalesced).
// ---------------------------------------------------------------------------
__global__ __launch_bounds__(256, 2) void gemm_kernel(
    const float* __restrict__ x, const float* __restrict__ ex,
    const float* __restrict__ W, const float* __restrict__ tgt,
    const unsigned short* __restrict__ sigb,
    const unsigned short* __restrict__ Abf,
    float* __restrict__ out0, float* __restrict__ out1,
    float* __restrict__ out2)
{
    __shared__ __align__(16) char lds[3 * BUF];

    // ---- block mapping: same-bm blocks share an XCD (x/sig L2 reuse)
    const int b     = blockIdx.x;
    const int xcd   = b & 7;
    const int local = b >> 3;                    // 0..127
    const int bm    = xcd * 8 + (local >> 4);    // 0..63
    const int bn    = local & 15;                // 0..15

    const int tid  = threadIdx.x;
    const int lane = tid & 63;
    const int wid  = tid >> 6;                   // 0..3
    const int wr   = wid >> 1, wc = wid & 1;
    const int l15  = lane & 15;

    // ---- staging source addresses (pre-swizzled source, linear LDS dest)
    const int swz = (((lane & 7) ^ (lane >> 3)) << 4);
    const char* gS = (const char*)sigb +
        ((size_t)(bm * BM + wid * 8 + (lane >> 3)) * DIM) * 2 + swz;
    const char* gB = (const char*)Abf +
        ((size_t)(bn * BN + wid * 8 + (lane >> 3)) * DIM) * 2 + swz;

    // ---- fragment read constants (R9-verified)
    const int rd_sw = (lane & 7) << 4;
    const int cb0   = (lane >> 4) << 4;

    f32x4 acc[4][2];
#pragma unroll
    for (int mi = 0; mi < 4; ++mi)
#pragma unroll
        for (int ni = 0; ni < 2; ++ni)
            acc[mi][ni] = f32x4{0.f, 0.f, 0.f, 0.f};

    auto stage = [&](int t) {                    // 6 glds per wave
        char* As = lds + (t % 3) * BUF;
        char* Bs = As + 16384;
        const size_t ko = (size_t)t * (BK * 2);
#pragma unroll
        for (int j = 0; j < 4; ++j)
            __builtin_amdgcn_global_load_lds(
                AS1(gS + (size_t)j * (32 * DIM * 2) + ko),
                AS3(As + (wid * 8 + j * 32) * 128), 16, 0, 0);
#pragma unroll
        for (int j = 0; j < 2; ++j)
            __builtin_amdgcn_global_load_lds(
                AS1(gB + (size_t)j * (32 * DIM * 2) + ko),
                AS3(Bs + (wid * 8 + j * 32) * 128), 16, 0, 0);
    };

    // ---- prologue: two stages in flight
    stage(0);
    stage(1);

    // ---- main loop: one counted wait + one raw barrier per step
    for (int t = 0; t < STEPS; ++t) {
        __builtin_amdgcn_sched_barrier(0);
        if (t < STEPS - 1) asm volatile("s_waitcnt vmcnt(6)" ::: "memory");
        else               asm volatile("s_waitcnt vmcnt(0)" ::: "memory");
        __builtin_amdgcn_sched_barrier(0);
        __builtin_amdgcn_s_barrier();
        __builtin_amdgcn_sched_barrier(0);
        if (t + 2 < STEPS) stage(t + 2);
        __builtin_amdgcn_sched_barrier(0);

        const char* As_ = lds + (t % 3) * BUF;
        const char* Bs_ = As_ + 16384;
#pragma unroll
        for (int kk = 0; kk < 2; ++kk) {
            bf16x8 af[4], bfr[2];
#pragma unroll
            for (int mi = 0; mi < 4; ++mi)
                af[mi] = *(const bf16x8*)(As_ + (wr * 64 + mi * 16 + l15) * 128 +
                                          ((cb0 + kk * 64) ^ rd_sw));
#pragma unroll
            for (int ni = 0; ni < 2; ++ni)
                bfr[ni] = *(const bf16x8*)(Bs_ + (wc * 32 + ni * 16 + l15) * 128 +
                                           ((cb0 + kk * 64) ^ rd_sw));
#pragma unroll
            for (int mi = 0; mi < 4; ++mi)
#pragma unroll
                for (int ni = 0; ni < 2; ++ni)
                    acc[mi][ni] = __builtin_amdgcn_mfma_f32_16x16x32_bf16(
                        af[mi], bfr[ni], acc[mi][ni], 0, 0, 0);
        }
    }

    // ---- epilogue: C -> LDS f32[128][64] (linear), then streaming pass
    __syncthreads();
#pragma unroll
    for (int mi = 0; mi < 4; ++mi)
#pragma unroll
        for (int ni = 0; ni < 2; ++ni) {
            const int row_ = wr * 64 + mi * 16 + ((lane >> 4) << 2);
            const int colb = (wc * 32 + ni * 16 + l15) * 4;
#pragma unroll
            for (int r = 0; r < 4; ++r)
                *(float*)(lds + (row_ + r) * 256 + colb) = acc[mi][ni][r];
        }
    __syncthreads();

#pragma unroll
    for (int p = 0; p < 8; ++p) {
        const int ci  = p * 256 + tid;           // 0..2047
        const int row = ci >> 4;                 // 0..127
        const int cv  = ci & 15;                 // 0..15
        f32x4 c = *(const f32x4*)(lds + row * 256 + cv * 16);
        const size_t v4 = (size_t)(bm * BM + row) * (DIM / 4) + bn * 16 + cv;
        f32x4 xv = ((const f32x4*)x)[v4];
        f32x4 ev = ((const f32x4*)ex)[v4];
        f32x4 wv = ((const f32x4*)W)[v4];
        f32x4 tv = ((const f32x4*)tgt)[bn * 16 + cv];
        f32x4 o0;
#pragma unroll
        for (int e = 0; e < 4; ++e) {
            float xi = xv[e], ti = tv[e];
            float ba = ti * ti * __builtin_amdgcn_rcpf(1.0f + ti * ti);
            float u  = -(wv[e] * (xi + ev[e] - ti)) * ba;
            float s  = sigma_f(xi);
            o0[e] = -xi + u * s + c[e];
        }
        ((f32x4*)out0)[v4] = o0;
        ((f32x4*)out1)[v4] = -o0;
        ((f32x4*)out2)[v4] = f32x4{0.f, 0.f, 0.f, 0.f};
    }
}

// ---------------------------------------------------------------------------
extern "C" void kernel_launch(void* const* d_in, const int* in_sizes, int n_in,
                              void* d_out, int out_size, void* d_ws, size_t ws_size,
                              hipStream_t stream)
{
    const float* x   = (const float*)d_in[0];
    const float* ex  = (const float*)d_in[1];
    const float* W   = (const float*)d_in[2];
    const float* A   = (const float*)d_in[3];
    const float* tgt = (const float*)d_in[4];

    float* out0 = (float*)d_out;
    float* out1 = out0 + (size_t)BATCH * DIM;
    float* out2 = out1 + (size_t)BATCH * DIM;

    unsigned short* sigb = (unsigned short*)d_ws;                                   // 16 MiB
    unsigned short* Abf  = (unsigned short*)((char*)d_ws + (size_t)16 * 1024 * 1024); // 2 MiB

    prep_kernel<<<4608, 256, 0, stream>>>(x, A, sigb, Abf);
    gemm_kernel<<<(BATCH / BM) * (DIM / BN), 256, 0, stream>>>(
        x, ex, W, tgt, sigb, Abf, out0, out1, out2);
}